// Round 2
// baseline (193.948 us; speedup 1.0000x reference)
//
#include <hip/hip_runtime.h>

// ValueDVHLoss via the Wasserstein/CDF identity:
//   sum_i |a_(i) - b_(i)| = integral |#{a<=t} - #{b<=t}| dt
// R14: barrier-free direct-load hist. R13's counted-vmcnt depth-2 pipeline
// was ALSO invariant (190.1 vs 190.9) -- convoy theory falsified. hist's
// ~50us floor has now survived: load scheme, occupancy-within-staging, bank
// conflicts, bins, atomic count/width, and true software pipelining. The
// never-varied constants are (a) DMA-into-LDS sharing banks/pipe with the
// LDS atomics, (b) 16 waves/CU cap from staging LDS, (c) barrier-phase-locked
// waves. Data has ZERO reuse -- only the 24KB hist belongs in LDS. So: drop
// staging entirely. Straight-line per-thread: 8 voxels = 4x float4 + 6x int2
// independent loads (full MLP), zero barriers in the hot path, 24.6KB LDS,
// __launch_bounds__(512,8) -> 32 waves/CU, 1024 blocks (CHUNK=4096).
// seg_scan: 256 partials/segment (quarters of 64). Predict hist 50->~15us,
// total ~160. If invariant again: floor is intrinsic to LDS-atomic hist.

#define NBINS 1024
#define NB1   (NBINS - 1)
#define RROI  6
#define BPAT  4
#define NSEG  24                 // seg = r*BPAT + b
#define VVOX  1048576            // voxels per patient (C=1)
#define BLKP  256                // hist blocks per patient
#define GRID1 (BPAT * BLKP)      // 1024 blocks = 4/CU
#define CHUNK (VVOX / BLKP)      // 4096 voxels per block
#define HW    (NBINS / 2)        // 512 packed words per (block,roi)

// LDS: hist 6x1024 ints @ 0 (24KB), merge scratch @ 6144
#define BUF_I  6144
#define LDS_INTS 6160

// ws layout (int indices)
#define PART_I 0
#define PART_N (GRID1 * RROI * HW)        // 3,145,728 ints (12.6 MB)
#define CNT6_I (PART_I + PART_N)
#define CNT6_N (GRID1 * RROI)             // 6144
#define FH_I   (CNT6_I + CNT6_N)
#define FH_N   (NSEG * NBINS)             // 24576
#define DONE_I (FH_I + FH_N)              // 24
#define SEGD_I (DONE_I + NSEG)            // 1
#define ZERO_I FH_I
#define ZERO_N (FH_N + NSEG + 1)          // 24601 (zeroed by hist blocks)
#define S_I    (SEGD_I + 1)               // 24 floats
#define DEN_I  (S_I + NSEG)               // 24

// ---- phase 1: per-chunk histogram over all 6 ROIs, direct loads ----------
__global__ __launch_bounds__(512, 8) void hist_kernel(
    const float* __restrict__ pred, const float* __restrict__ tgt,
    const void* __restrict__ mask, int* __restrict__ ws) {
  __shared__ __align__(16) int lds[LDS_INTS];   // 24.6 KB
  const int tid  = threadIdx.x;
  const int lane = tid & 63;
  const int flat = blockIdx.x;          // 0..1023
  const int b    = flat >> 8;           // patient
  const int nb   = flat & (BLKP - 1);
  const int v0   = nb * CHUNK;

  const unsigned int* mwp = (const unsigned int*)mask;
  const int byteLayout = __any(mwp[tid] > 1u);

  for (int i = tid; i < 6144; i += 512) lds[i] = 0;
  if (flat < 128 && tid < 193) {        // pre-zero dispatch-2 counters
    int zi = flat * 193 + tid;
    if (zi < ZERO_N) ws[ZERO_I + zi] = 0;
  }

  int c01 = 0, c23 = 0, c45 = 0;
  __syncthreads();   // hist zero visible before any atomics

  // voxel: 6 mask bits at shift SH of the 6 mask dwords; bin once per voxel
#define VOX(SH, M, PP, GG)                                                   \
  {                                                                          \
    int a01 = (((M)[0] >> (SH)) & 1) | ((((M)[1] >> (SH)) & 1) << 16);       \
    int a23 = (((M)[2] >> (SH)) & 1) | ((((M)[3] >> (SH)) & 1) << 16);       \
    int a45 = (((M)[4] >> (SH)) & 1) | ((((M)[5] >> (SH)) & 1) << 16);       \
    int bp = min((int)((PP) * 1024.0f), NB1);                                \
    int bg = min((int)((GG) * 1024.0f), NB1);                                \
    atomicAdd(&lds[bp],        a01); atomicAdd(&lds[1024 + bp], a23);        \
    atomicAdd(&lds[2048 + bp], a45);                                         \
    atomicAdd(&lds[3072 + bg], a01); atomicAdd(&lds[4096 + bg], a23);        \
    atomicAdd(&lds[5120 + bg], a45);                                         \
    c01 += a01; c23 += a23; c45 += a45;                                      \
  }

  if (byteLayout) {
    // straight-line: this thread owns voxels [v0 + tid*8, v0 + tid*8 + 8)
    const float4* p4 = (const float4*)(pred + (size_t)b * VVOX + v0);
    const float4* g4 = (const float4*)(tgt  + (size_t)b * VVOX + v0);
    const char* mbase = (const char*)mask;

    float4 pv0 = p4[2 * tid], pv1 = p4[2 * tid + 1];
    float4 gv0 = g4[2 * tid], gv1 = g4[2 * tid + 1];
    unsigned mx[RROI], my[RROI];
#pragma unroll
    for (int r = 0; r < RROI; r++) {
      int2 mm = ((const int2*)(mbase + (size_t)(r * BPAT + b) * VVOX + v0))[tid];
      mx[r] = (unsigned)mm.x; my[r] = (unsigned)mm.y;
    }
    VOX(0,  mx, pv0.x, gv0.x)
    VOX(8,  mx, pv0.y, gv0.y)
    VOX(16, mx, pv0.z, gv0.z)
    VOX(24, mx, pv0.w, gv0.w)
    VOX(0,  my, pv1.x, gv1.x)
    VOX(8,  my, pv1.y, gv1.y)
    VOX(16, my, pv1.z, gv1.z)
    VOX(24, my, pv1.w, gv1.w)
  } else {  // int32 masks — correctness-only path, direct loads
    const int* mi = (const int*)mask;
    const float4* p4 = (const float4*)(pred + (size_t)b * VVOX + v0);
    const float4* g4 = (const float4*)(tgt  + (size_t)b * VVOX + v0);
    for (int pk = tid; pk < CHUNK / 4; pk += 512) {
      float4 pv = p4[pk], gv = g4[pk];
      unsigned m0[RROI], m1[RROI], m2[RROI], m3[RROI];
#pragma unroll
      for (int r = 0; r < RROI; r++) {
        int4 mm = ((const int4*)(mi + (size_t)(r * BPAT + b) * VVOX + v0))[pk];
        m0[r] = mm.x; m1[r] = mm.y; m2[r] = mm.z; m3[r] = mm.w;
      }
      VOX(0, m0, pv.x, gv.x)
      VOX(0, m1, pv.y, gv.y)
      VOX(0, m2, pv.z, gv.z)
      VOX(0, m3, pv.w, gv.w)
    }
  }
#undef VOX

  // count merge
  if (tid < 3) lds[BUF_I + tid] = 0;
  __syncthreads();
  for (int off = 32; off > 0; off >>= 1) {
    c01 += __shfl_down(c01, off, 64);
    c23 += __shfl_down(c23, off, 64);
    c45 += __shfl_down(c45, off, 64);
  }
  if (lane == 0) {
    atomicAdd(&lds[BUF_I], c01); atomicAdd(&lds[BUF_I + 1], c23);
    atomicAdd(&lds[BUF_I + 2], c45);
  }
  __syncthreads();

  // write signed int16 diffs (pred-tgt), 2 bins per int
  for (int idx = tid; idx < RROI * HW; idx += 512) {   // 6 iters
    int r = idx >> 9, wd = idx & (HW - 1);
    int k = r >> 1, f = (r & 1) << 4;
    int b0 = 2 * wd, b1 = b0 + 1;
    int d0 = ((lds[k * 1024 + b0] >> f) & 0xffff) -
             ((lds[(3 + k) * 1024 + b0] >> f) & 0xffff);
    int d1 = ((lds[k * 1024 + b1] >> f) & 0xffff) -
             ((lds[(3 + k) * 1024 + b1] >> f) & 0xffff);
    ws[PART_I + (size_t)(flat * RROI + r) * HW + wd] = (d0 & 0xffff) | (d1 << 16);
  }
  if (tid < RROI) {
    int p = lds[BUF_I + (tid >> 1)];
    int c = (tid & 1) ? ((p >> 16) & 0xffff) : (p & 0xffff);
    ws[CNT6_I + flat * RROI + tid] = c;
  }
}

// ---- phase 2: reduce quarters -> global merge -> winner scan -> finalize -
__global__ __launch_bounds__(256) void seg_scan(int* __restrict__ ws,
                                                float* __restrict__ out) {
  const int bq  = blockIdx.x;          // 0..95
  const int seg = bq >> 2, q = bq & 3;
  const int r   = seg >> 2, b = seg & 3;
  const int t   = threadIdx.x;         // 256 threads; each owns bins 4t..4t+3

  int s[4] = {0, 0, 0, 0};
#pragma unroll 4
  for (int nb = q * 64; nb < q * 64 + 64; nb++) {
    const int2 wv = ((const int2*)(ws + PART_I +
                     (size_t)((b * BLKP + nb) * RROI + r) * HW))[t];
    s[0] += (int)(short)(wv.x & 0xffff); s[1] += wv.x >> 16;
    s[2] += (int)(short)(wv.y & 0xffff); s[3] += wv.y >> 16;
  }
  int* fh = ws + FH_I + seg * NBINS + 4 * t;
#pragma unroll
  for (int k = 0; k < 4; k++)
    if (s[k]) atomicAdd(&fh[k], s[k]);
  __threadfence();
  __shared__ int winflag;
  if (t == 0) winflag = (atomicAdd(ws + DONE_I + seg, 1) == 3);
  __syncthreads();
  if (!winflag) return;

  int bins[4];
#pragma unroll
  for (int k = 0; k < 4; k++)
    bins[k] = __hip_atomic_load(&fh[k], __ATOMIC_RELAXED,
                                __HIP_MEMORY_SCOPE_AGENT);
  int dv = ws[CNT6_I + (b * BLKP + t) * RROI + r];   // 256 partial counts

  int tot = 0;
#pragma unroll
  for (int k = 0; k < 4; k++) { tot += bins[k]; bins[k] = tot; }
  const int lane = t & 63, wid = t >> 6;       // 4 waves
  int v = tot;
  for (int off = 1; off < 64; off <<= 1) {
    int u = __shfl_up(v, off, 64);
    if (lane >= off) v += u;
  }
  __shared__ int wsum[4]; __shared__ unsigned long long lsum[4];
  __shared__ int dsum[4];
  if (lane == 63) wsum[wid] = v;
  for (int off = 32; off > 0; off >>= 1) dv += __shfl_down(dv, off, 64);
  if (lane == 0) dsum[wid] = dv;
  __syncthreads();
  int woff = 0;
  for (int w = 0; w < wid; w++) woff += wsum[w];
  const int excl = woff + v - tot;
  unsigned long long acc = 0;
#pragma unroll
  for (int k = 0; k < 4; k++) {
    int c = excl + bins[k];
    acc += (unsigned long long)(c < 0 ? -c : c);
  }
  for (int off = 32; off > 0; off >>= 1) acc += __shfl_down(acc, off, 64);
  if (lane == 0) lsum[wid] = acc;
  __syncthreads();

  if (t == 0) {
    unsigned long long a = 0; int d = 0;
    for (int w = 0; w < 4; w++) { a += lsum[w]; d += dsum[w]; }
    ((float*)ws)[S_I + seg] = (float)((double)a * (52.0 / (double)NBINS));
    ws[DEN_I + seg] = d;
    __threadfence();
    if (atomicAdd(ws + SEGD_I, 1) == NSEG - 1) {   // last segment finalizes
      float total = 0.f; int nv = 0;
      for (int bb = 0; bb < BPAT; bb++) {
        float num = 0.f; long long dd = 0;
        for (int rr = 0; rr < RROI; rr++) {
          num += __hip_atomic_load(&((float*)ws)[S_I + rr * BPAT + bb],
                                   __ATOMIC_RELAXED, __HIP_MEMORY_SCOPE_AGENT);
          dd  += __hip_atomic_load(&ws[DEN_I + rr * BPAT + bb],
                                   __ATOMIC_RELAXED, __HIP_MEMORY_SCOPE_AGENT);
        }
        if (dd > 0) { total += num / fmaxf((float)dd, 1.f); nv++; }
      }
      out[0] = total / (float)(nv > 0 ? nv : 1);
    }
  }
}

extern "C" void kernel_launch(void* const* d_in, const int* in_sizes, int n_in,
                              void* d_out, int out_size, void* d_ws,
                              size_t ws_size, hipStream_t stream) {
  const float* pred = (const float*)d_in[0];
  const float* tgt  = (const float*)d_in[1];
  const void* mask  = d_in[2];
  int* ws = (int*)d_ws;   // needs ~13 MB; d_ws is 384 MiB

  hist_kernel<<<GRID1, 512, 0, stream>>>(pred, tgt, mask, ws);
  seg_scan<<<NSEG * 4, 256, 0, stream>>>(ws, (float*)d_out);
}